// Round 2
// baseline (456.528 us; speedup 1.0000x reference)
//
#include <hip/hip_runtime.h>
#include <hip/hip_bf16.h>
#include <stdint.h>

// Problem constants
#define L_DIM 4096
#define B_DIM 32
#define H_DIM 512
#define M_DIM (L_DIM * B_DIM)  // 131072 rows of the fused GEMM
#define K_DIM H_DIM            // 512 reduction dim

typedef _Float16 half8 __attribute__((ext_vector_type(8)));
typedef __fp16 fp16x2 __attribute__((ext_vector_type(2)));  // cvt_pkrtz return type
typedef float floatx4 __attribute__((ext_vector_type(4)));

// tanh(x) = 1 - 2/(1 + e^{2x}), via hw exp2 + rcp (~1e-7 abs err, saturates correctly)
__device__ __forceinline__ float tanh_fast(float x) {
  float e = __builtin_amdgcn_exp2f(x * 2.88539008177793f);  // 2*log2(e)
  return 1.0f - 2.0f * __builtin_amdgcn_rcpf(e + 1.0f);
}

// async global->LDS, 16B per lane; LDS dst is wave-uniform base + lane*16
__device__ __forceinline__ void async_copy16(const _Float16* g, _Float16* l) {
  __builtin_amdgcn_global_load_lds(
      (__attribute__((address_space(1))) unsigned int*)(const_cast<_Float16*>(g)),
      (__attribute__((address_space(3))) unsigned int*)(l),
      16, 0, 0);
}

// ---------------------------------------------------------------------------
// q_proj[b][h] = sum_i query[b][i] * W[i][h]   (fp32, exact; 32x512 output)
// grid: 32 blocks (one per b) x 128 threads (4 cols each)
__global__ __launch_bounds__(128) void qproj_kernel(const float* __restrict__ query,
                                                    const float* __restrict__ W,
                                                    float* __restrict__ qp) {
  const int b = blockIdx.x;
  const int h = threadIdx.x * 4;
  const float* qrow = query + b * H_DIM;
  float4 acc = make_float4(0.f, 0.f, 0.f, 0.f);
#pragma unroll 8
  for (int i = 0; i < K_DIM; ++i) {
    const float qv = qrow[i];
    const float4 w4 = *(const float4*)(W + (size_t)i * H_DIM + h);
    acc.x += qv * w4.x; acc.y += qv * w4.y;
    acc.z += qv * w4.z; acc.w += qv * w4.w;
  }
  *(float4*)(qp + (size_t)b * H_DIM + h) = acc;
}

// ---------------------------------------------------------------------------
// Build W2: Wk (=W[512:]) as fp16, tiled [kt][n][s] in 16B chunks with XOR-swizzle
// so global_load_lds's forced lane-contiguous LDS layout is bank-conflict-light.
// LDS chunk at (n, s) must hold B[k = kt*32 + (s ^ ((n>>1)&3))*8 + j][n], j=0..7.
// grid: 128 blocks x 256 threads, one 16B chunk per thread.
__global__ __launch_bounds__(256) void wconv_kernel(const float* __restrict__ W,
                                                    _Float16* __restrict__ W2) {
  const int t = blockIdx.x * 256 + threadIdx.x;  // [0, 32768)
  const int s = t & 3;
  const int n = (t >> 2) & 511;
  const int kt = t >> 11;
  const int kseg = s ^ ((n >> 1) & 3);
  const int kbase = H_DIM + kt * 32 + kseg * 8;  // Wk rows live at W[512 + k]
  half8 h;
#pragma unroll
  for (int j = 0; j < 8; ++j)
    h[j] = (_Float16)W[(size_t)(kbase + j) * H_DIM + n];
  *(half8*)(W2 + (size_t)t * 8) = h;
}

// ---------------------------------------------------------------------------
// Fused GEMM + tanh + v-dot. Block: 64 rows (m) x 512 cols (full H) so key_val
// is read exactly once from HBM. 256 thr = 4 waves; wave w owns n-slice w*128.
// 16x16x32 f16 MFMA, 4x8 frags/wave, acc 128 VGPR/thr -> 2 blocks/CU.
__global__ __launch_bounds__(256, 2) void fused_gemm_kernel(
    const float* __restrict__ key, const _Float16* __restrict__ W2,
    const float* __restrict__ qp, const float* __restrict__ v,
    float* __restrict__ scores) {
  __shared__ __align__(16) _Float16 As[64 * 40];   // pad 32->40 halves: frag reads 2-way only
  __shared__ __align__(16) _Float16 Bs[512 * 32];  // swizzled chunk layout, 32 KB
  __shared__ float swave[256];

  const int tid = threadIdx.x;
  const int lane = tid & 63;
  const int w = tid >> 6;
  const int l15 = lane & 15;
  const int quad = lane >> 4;
  const int m0 = blockIdx.x * 64;

  // A staging: thread t loads 8 fp32 of row (t>>2), k-seg (t&3)*8, cvt->fp16
  const int am = tid >> 2;
  const int aks = (tid & 3) * 8;
  const float* ag = key + (size_t)(m0 + am) * K_DIM + aks;
  _Float16* asdst = As + am * 40 + aks;  // byte offset m*80 + seg*16: 16B aligned

  // B staging: wave w, call c, lane -> chunk c*256 + w*64 + lane
  const _Float16* bg = W2 + (size_t)(w * 64 + lane) * 8;
  _Float16* bdst0 = Bs + (size_t)(w * 64) * 8;  // + c*2048 halves per call

  // fragment LDS offsets (constant across K loop: single buffer)
  int aoff[4];
#pragma unroll
  for (int fm = 0; fm < 4; ++fm) aoff[fm] = (fm * 16 + l15) * 40 + quad * 8;
  int boff[8];
#pragma unroll
  for (int fn = 0; fn < 8; ++fn) {
    const int n = w * 128 + fn * 16 + l15;
    boff[fn] = n * 32 + (quad ^ ((n >> 1) & 3)) * 8;
  }

  floatx4 acc[4][8];
#pragma unroll
  for (int fm = 0; fm < 4; ++fm)
#pragma unroll
    for (int fn = 0; fn < 8; ++fn) acc[fm][fn] = (floatx4)0.0f;

  for (int kt = 0; kt < 16; ++kt) {
    // prefetch A into regs before the barrier
    const float4 f0 = *(const float4*)(ag + kt * 32);
    const float4 f1 = *(const float4*)(ag + kt * 32 + 4);
    __syncthreads();  // previous iteration's frag reads done
    // A: cvt fp32->fp16 (pack RTZ), one ds_write_b128
    const fp16x2 p0 = __builtin_amdgcn_cvt_pkrtz(f0.x, f0.y);
    const fp16x2 p1 = __builtin_amdgcn_cvt_pkrtz(f0.z, f0.w);
    const fp16x2 p2 = __builtin_amdgcn_cvt_pkrtz(f1.x, f1.y);
    const fp16x2 p3 = __builtin_amdgcn_cvt_pkrtz(f1.z, f1.w);
    uint4 u;
    u.x = __builtin_bit_cast(unsigned, p0);
    u.y = __builtin_bit_cast(unsigned, p1);
    u.z = __builtin_bit_cast(unsigned, p2);
    u.w = __builtin_bit_cast(unsigned, p3);
    *(uint4*)asdst = u;
    // B: 8 async 1KB/wave copies (pre-swizzled in W2, LDS layout inherits swizzle)
    const _Float16* bsrc = bg + (size_t)kt * 16384;
#pragma unroll
    for (int c = 0; c < 8; ++c) async_copy16(bsrc + c * 2048, bdst0 + c * 2048);
    __syncthreads();  // barrier waitcnt drains vmcnt (incl. lds-DMA) + lgkm

    half8 av[4];
#pragma unroll
    for (int fm = 0; fm < 4; ++fm) av[fm] = *(const half8*)(As + aoff[fm]);
    half8 bv[8];
#pragma unroll
    for (int fn = 0; fn < 8; ++fn) bv[fn] = *(const half8*)(Bs + boff[fn]);
#pragma unroll
    for (int fm = 0; fm < 4; ++fm)
#pragma unroll
      for (int fn = 0; fn < 8; ++fn)
        acc[fm][fn] = __builtin_amdgcn_mfma_f32_16x16x32_f16(av[fm], bv[fn],
                                                             acc[fm][fn], 0, 0, 0);
  }

  // Epilogue: score[m] = sum_n v[n] * tanh(qp[m&31][n] + kproj[m][n])
  // C/D layout: col = lane&15, row = quad*4 + reg (m89, dtype-independent)
  float vv[8];
#pragma unroll
  for (int fn = 0; fn < 8; ++fn) vv[fn] = v[w * 128 + fn * 16 + l15];

#pragma unroll
  for (int fm = 0; fm < 4; ++fm) {
#pragma unroll
    for (int r = 0; r < 4; ++r) {
      const int mrow = fm * 16 + quad * 4 + r;
      const float* qrow = qp + (size_t)(mrow & 31) * H_DIM;
      float rs = 0.f;
#pragma unroll
      for (int fn = 0; fn < 8; ++fn) {
        const int n = w * 128 + fn * 16 + l15;
        const float x = qrow[n] + acc[fm][fn][r];
        rs += vv[fn] * tanh_fast(x);
      }
      // reduce over the 16 lanes (same row, different n) of this quad
      rs += __shfl_xor(rs, 1);
      rs += __shfl_xor(rs, 2);
      rs += __shfl_xor(rs, 4);
      rs += __shfl_xor(rs, 8);
      if (l15 == 0) swave[w * 64 + mrow] = rs;
    }
  }
  __syncthreads();
  if (tid < 64) {
    const float s = swave[tid] + swave[64 + tid] + swave[128 + tid] + swave[192 + tid];
    scores[(size_t)m0 + tid] = s;  // scores[m], m = l*32 + b
  }
}

// ---------------------------------------------------------------------------
// softmax over l per b; scores stored as [m = l*32 + b]; out[b][l]
__global__ __launch_bounds__(256) void softmax_kernel(const float* __restrict__ scores,
                                                      float* __restrict__ out) {
  const int b = blockIdx.x;
  const int t = threadIdx.x;
  __shared__ float red[256];
  float s[16];
#pragma unroll
  for (int i = 0; i < 16; ++i) s[i] = scores[(size_t)(t + i * 256) * B_DIM + b];
  float mx = s[0];
#pragma unroll
  for (int i = 1; i < 16; ++i) mx = fmaxf(mx, s[i]);
  red[t] = mx;
  __syncthreads();
  for (int off = 128; off > 0; off >>= 1) {
    if (t < off) red[t] = fmaxf(red[t], red[t + off]);
    __syncthreads();
  }
  mx = red[0];
  __syncthreads();
  float sum = 0.f;
#pragma unroll
  for (int i = 0; i < 16; ++i) {
    s[i] = __builtin_amdgcn_exp2f((s[i] - mx) * 1.44269504f);
    sum += s[i];
  }
  red[t] = sum;
  __syncthreads();
  for (int off = 128; off > 0; off >>= 1) {
    if (t < off) red[t] += red[t + off];
    __syncthreads();
  }
  const float inv = 1.0f / red[0];
#pragma unroll
  for (int i = 0; i < 16; ++i) out[(size_t)b * L_DIM + t + i * 256] = s[i] * inv;
}

// ---------------------------------------------------------------------------
extern "C" void kernel_launch(void* const* d_in, const int* in_sizes, int n_in,
                              void* d_out, int out_size, void* d_ws, size_t ws_size,
                              hipStream_t stream) {
  const float* query = (const float*)d_in[0];
  const float* key   = (const float*)d_in[1];
  const float* W     = (const float*)d_in[2];
  const float* v     = (const float*)d_in[3];
  float* out = (float*)d_out;

  char* ws = (char*)d_ws;
  float* qp       = (float*)ws;                        // 32*512*4   = 64 KB
  float* scores   = (float*)(ws + 65536);              // 131072*4   = 512 KB
  _Float16* W2    = (_Float16*)(ws + 65536 + 524288);  // 512*512*2  = 512 KB

  qproj_kernel<<<32, 128, 0, stream>>>(query, W, qp);
  wconv_kernel<<<128, 256, 0, stream>>>(W, W2);
  fused_gemm_kernel<<<M_DIM / 64, 256, 0, stream>>>(key, W2, qp, v, scores);
  softmax_kernel<<<B_DIM, 256, 0, stream>>>(scores, out);
}